// Round 3
// baseline (1654.370 us; speedup 1.0000x reference)
//
#include <hip/hip_runtime.h>

#define N_NODES 100000
#define IN_F 256
#define OUT_F 128
#define NB 782        // row buckets of 128 rows
#define CAP 2560      // per-bucket edge capacity (mean 2048, sigma 45 -> 11 sigma headroom)
#define TILE 4096     // edges per scatter block

typedef __attribute__((ext_vector_type(8))) short v8s;
typedef __attribute__((ext_vector_type(4))) float v4f;

__device__ __forceinline__ unsigned short f2bf(float f) {
    unsigned int u = __float_as_uint(f);
    u += 0x7fffu + ((u >> 16) & 1u);
    return (unsigned short)(u >> 16);
}
__device__ __forceinline__ float bf2f(unsigned short s) {
    return __uint_as_float((unsigned int)s << 16);
}

// dropout + cast: xb = bf16(dropout(input))   [pure streaming, 256 MB]
__global__ __launch_bounds__(256) void drop_kernel(
    const float* __restrict__ x, const float* __restrict__ u,
    unsigned short* __restrict__ xb, int n4) {
    int i = blockIdx.x * 256 + threadIdx.x;
    int stride = gridDim.x * 256;
    for (; i < n4; i += stride) {
        float4 xi = ((const float4*)x)[i];
        float4 du = ((const float4*)u)[i];
        ushort4 pk;
        pk.x = f2bf(du.x > 0.2f ? xi.x * 1.25f : 0.0f);
        pk.y = f2bf(du.y > 0.2f ? xi.y * 1.25f : 0.0f);
        pk.z = f2bf(du.z > 0.2f ? xi.z * 1.25f : 0.0f);
        pk.w = f2bf(du.w > 0.2f ? xi.w * 1.25f : 0.0f);
        ((ushort4*)xb)[i] = pk;
    }
}

// weight [K=256][F=128] fp32 -> bt bf16 [F=128][K=256]
__global__ void wt_kernel(const float* __restrict__ w, unsigned short* __restrict__ bt) {
    int idx = blockIdx.x * 256 + threadIdx.x;
    int k = idx >> 7;
    int n = idx & 127;
    bt[n * IN_F + k] = f2bf(w[idx]);
}

// thin bf16 GEMM: support[N][128] (bf16) = xb @ bt^T
__global__ __launch_bounds__(256) void gemm_kernel(
    const unsigned short* __restrict__ xb, const unsigned short* __restrict__ bt,
    unsigned short* __restrict__ support) {
    __shared__ unsigned short As[128 * 72];
    __shared__ unsigned short Bs[128 * 72];

    const int tid  = threadIdx.x;
    const int lane = tid & 63;
    const int wv   = tid >> 6;
    const int wr   = wv >> 1, wc = wv & 1;
    const long long base = (long long)blockIdx.x * 128;

    v4f acc[4][4] = {};

    for (int k0 = 0; k0 < IN_F; k0 += 64) {
        if (k0) __syncthreads();
        {   // stage A: rows base..base+127, k0..k0+63 from xb
            const int row = tid >> 1;
            const int kh  = (tid & 1) * 32;
            long long g = base + row;
            unsigned short* dst = &As[row * 72 + kh];
            if (g < N_NODES) {
                const unsigned short* src = xb + g * IN_F + k0 + kh;
                #pragma unroll
                for (int i = 0; i < 4; ++i)
                    *(v8s*)(dst + i * 8) = *(const v8s*)(src + i * 8);
            } else {
                #pragma unroll
                for (int i = 0; i < 4; ++i)
                    *(v8s*)(dst + i * 8) = (v8s){0,0,0,0,0,0,0,0};
            }
        }
        {   // stage B^T
            const int n  = tid >> 1;
            const int kh = (tid & 1) * 32;
            const unsigned short* src = bt + n * IN_F + k0 + kh;
            unsigned short* dst = &Bs[n * 72 + kh];
            #pragma unroll
            for (int i = 0; i < 4; ++i)
                *(v8s*)(dst + i * 8) = *(const v8s*)(src + i * 8);
        }
        __syncthreads();
        #pragma unroll
        for (int ks = 0; ks < 2; ++ks) {
            const int kb = ks * 32 + (lane >> 4) * 8;
            v8s af[4], bf[4];
            #pragma unroll
            for (int t = 0; t < 4; ++t)
                af[t] = *(const v8s*)&As[(wr * 64 + t * 16 + (lane & 15)) * 72 + kb];
            #pragma unroll
            for (int t = 0; t < 4; ++t)
                bf[t] = *(const v8s*)&Bs[(wc * 64 + t * 16 + (lane & 15)) * 72 + kb];
            #pragma unroll
            for (int tm = 0; tm < 4; ++tm)
                #pragma unroll
                for (int tn = 0; tn < 4; ++tn)
                    acc[tm][tn] = __builtin_amdgcn_mfma_f32_16x16x32_bf16(
                        af[tm], bf[tn], acc[tm][tn], 0, 0, 0);
        }
    }
    const int rq = lane >> 4;
    const int cl = lane & 15;
    #pragma unroll
    for (int tm = 0; tm < 4; ++tm) {
        #pragma unroll
        for (int r = 0; r < 4; ++r) {
            long long g = base + wr * 64 + tm * 16 + rq * 4 + r;
            if (g < N_NODES) {
                unsigned short* o = support + g * OUT_F + wc * 64 + cl;
                #pragma unroll
                for (int tn = 0; tn < 4; ++tn)
                    o[tn * 16] = f2bf(acc[tm][tn][r]);
            }
        }
    }
}

__global__ void init_kernel(int* __restrict__ cursor) {
    int i = blockIdx.x * 256 + threadIdx.x;
    if (i < NB) cursor[i * 16] = i * CAP;   // 64B-padded cursors
}

// coalesced bucket scatter: tile -> LDS hist -> scan -> reserve -> reorder -> run writes
__global__ __launch_bounds__(256) void scatter_kernel(
    const int* __restrict__ row, const int* __restrict__ col,
    const float* __restrict__ val, int* __restrict__ cursor,
    int2* __restrict__ cv, int E) {
    __shared__ int cnt[1024];
    __shared__ int loc[1024];
    __shared__ int delta[1024];
    __shared__ int tmp[256];
    __shared__ int gd[TILE];
    __shared__ int2 stage[TILE];
    __shared__ int total_s;
    const int tid = threadIdx.x;
    const int base_e = blockIdx.x * TILE;

    for (int i = tid; i < 1024; i += 256) cnt[i] = 0;
    __syncthreads();
    // A: histogram
    #pragma unroll
    for (int j = 0; j < TILE / 256; ++j) {
        int e = base_e + j * 256 + tid;
        if (e < E) atomicAdd(&cnt[row[e] >> 7], 1);
    }
    __syncthreads();
    // B: block exclusive scan (thread owns 4 contiguous buckets)
    int c0 = cnt[4*tid], c1 = cnt[4*tid+1], c2 = cnt[4*tid+2], c3 = cnt[4*tid+3];
    int s = c0 + c1 + c2 + c3;
    tmp[tid] = s;
    __syncthreads();
    #pragma unroll
    for (int d = 1; d < 256; d <<= 1) {
        int t = (tid >= d) ? tmp[tid - d] : 0;
        __syncthreads();
        tmp[tid] += t;
        __syncthreads();
    }
    int excl = tmp[tid] - s;
    loc[4*tid]   = excl;
    loc[4*tid+1] = excl + c0;
    loc[4*tid+2] = excl + c0 + c1;
    loc[4*tid+3] = excl + c0 + c1 + c2;
    if (tid == 255) total_s = tmp[255];
    __syncthreads();
    // B2: reserve global space per bucket, compute delta, reset cnt as local cursor
    for (int i = tid; i < NB; i += 256) {
        int c = cnt[i];
        int gbase = 0;
        if (c > 0) gbase = atomicAdd(&cursor[i * 16], c);
        delta[i] = gbase - loc[i];
        cnt[i] = loc[i];
    }
    __syncthreads();
    // C: local reorder into stage, record global destination
    #pragma unroll
    for (int j = 0; j < TILE / 256; ++j) {
        int e = base_e + j * 256 + tid;
        if (e < E) {
            int r = row[e];
            int b = r >> 7;
            int rank = atomicAdd(&cnt[b], 1);
            stage[rank] = make_int2(col[e] | ((r & 127) << 17), __float_as_int(val[e]));
            gd[rank] = delta[b] + rank;
        }
    }
    __syncthreads();
    // D: coalesced-run writes
    int total = total_s;
    for (int i = tid; i < total; i += 256)
        cv[gd[i]] = stage[i];
}

// fused segment reduction: one block per 128-row bucket, fp32 LDS accumulator
__global__ __launch_bounds__(256) void acc_kernel(
    const int* __restrict__ cursor, const int2* __restrict__ cv,
    const unsigned short* __restrict__ support, float* __restrict__ out) {
    __shared__ float acc[128 * 128];   // 64 KB
    const int tid = threadIdx.x;
    const int b = blockIdx.x;
    for (int i = tid; i < 4096; i += 256)
        *(float4*)&acc[i * 4] = make_float4(0.f, 0.f, 0.f, 0.f);
    __syncthreads();
    const int lane = tid & 63, w = tid >> 6;
    const int e0 = b * CAP;
    const int e1 = cursor[b * 16];
    for (int e = e0 + w * 4; e < e1; e += 16) {
        #pragma unroll
        for (int j = 0; j < 4; ++j) {
            int ee = e + j;
            int es = min(ee, e1 - 1);
            int2 c = cv[es];
            int colv = c.x & 131071;
            int rl = c.x >> 17;
            float v = (ee < e1) ? __int_as_float(c.y) : 0.0f;
            float g0 = bf2f(support[colv * OUT_F + lane]);
            float g1 = bf2f(support[colv * OUT_F + 64 + lane]);
            atomicAdd(&acc[rl * 128 + lane], v * g0);        // banks: 2-way alias, free
            atomicAdd(&acc[rl * 128 + 64 + lane], v * g1);
        }
    }
    __syncthreads();
    long long rowbase = (long long)b * 128;
    for (int i = tid; i < 4096; i += 256) {
        int rl = i >> 5;
        int c4 = (i & 31) * 4;
        long long g = rowbase + rl;
        if (g < N_NODES)
            *(float4*)(out + g * OUT_F + c4) = *(float4*)&acc[rl * 128 + c4];
    }
}

extern "C" void kernel_launch(void* const* d_in, const int* in_sizes, int n_in,
                              void* d_out, int out_size, void* d_ws, size_t ws_size,
                              hipStream_t stream) {
    const float* input   = (const float*)d_in[0];
    const float* weight  = (const float*)d_in[1];
    const int*   adj_row = (const int*)d_in[2];
    const int*   adj_col = (const int*)d_in[3];
    const float* adj_val = (const float*)d_in[4];
    const float* drop_u  = (const float*)d_in[5];
    float* out = (float*)d_out;
    const int E = in_sizes[2];

    // ws layout: bt 64K | xb bf16 51.2M (cv int2 16M aliases here - disjoint lifetime)
    //            | support bf16 25.6M | cursor 50K
    char* p = (char*)d_ws;
    unsigned short* bt      = (unsigned short*)p;  p += 65536;
    unsigned short* xb      = (unsigned short*)p;
    int2*           cv      = (int2*)p;            p += (size_t)N_NODES * IN_F * 2;
    unsigned short* support = (unsigned short*)p;  p += (size_t)N_NODES * OUT_F * 2;
    int*            cursor  = (int*)p;

    init_kernel<<<4, 256, 0, stream>>>(cursor);
    drop_kernel<<<2048, 256, 0, stream>>>(input, drop_u, xb, N_NODES * IN_F / 4);
    wt_kernel<<<128, 256, 0, stream>>>(weight, bt);
    gemm_kernel<<<(N_NODES + 127) / 128, 256, 0, stream>>>(xb, bt, support);
    scatter_kernel<<<(E + TILE - 1) / TILE, 256, 0, stream>>>(adj_row, adj_col, adj_val, cursor, cv, E);
    acc_kernel<<<NB, 256, 0, stream>>>(cursor, cv, support, out);
}

// Round 4
// 424.260 us; speedup vs baseline: 3.8994x; 3.8994x over previous
//
#include <hip/hip_runtime.h>

#define N_NODES 100000
#define IN_F 256
#define OUT_F 128
#define NB 782        // row buckets of 128 rows
#define CAP 2560      // per-bucket edge capacity (mean 2048, sigma 45 -> 11 sigma headroom)
#define TILE 4096     // edges per scatter block

typedef __attribute__((ext_vector_type(8))) short v8s;
typedef __attribute__((ext_vector_type(4))) float v4f;

__device__ __forceinline__ unsigned short f2bf(float f) {
    unsigned int u = __float_as_uint(f);
    u += 0x7fffu + ((u >> 16) & 1u);
    return (unsigned short)(u >> 16);
}
__device__ __forceinline__ float bf2f(unsigned short s) {
    return __uint_as_float((unsigned int)s << 16);
}

// dropout + cast: xb = bf16(dropout(input))   [pure streaming, 256 MB]
__global__ __launch_bounds__(256) void drop_kernel(
    const float* __restrict__ x, const float* __restrict__ u,
    unsigned short* __restrict__ xb, int n4) {
    int i = blockIdx.x * 256 + threadIdx.x;
    int stride = gridDim.x * 256;
    for (; i < n4; i += stride) {
        float4 xi = ((const float4*)x)[i];
        float4 du = ((const float4*)u)[i];
        ushort4 pk;
        pk.x = f2bf(du.x > 0.2f ? xi.x * 1.25f : 0.0f);
        pk.y = f2bf(du.y > 0.2f ? xi.y * 1.25f : 0.0f);
        pk.z = f2bf(du.z > 0.2f ? xi.z * 1.25f : 0.0f);
        pk.w = f2bf(du.w > 0.2f ? xi.w * 1.25f : 0.0f);
        ((ushort4*)xb)[i] = pk;
    }
}

// weight [K=256][F=128] fp32 -> bt bf16 [F=128][K=256]
__global__ void wt_kernel(const float* __restrict__ w, unsigned short* __restrict__ bt) {
    int idx = blockIdx.x * 256 + threadIdx.x;
    int k = idx >> 7;
    int n = idx & 127;
    bt[n * IN_F + k] = f2bf(w[idx]);
}

// thin bf16 GEMM: support[N][128] (bf16) = xb @ bt^T
__global__ __launch_bounds__(256) void gemm_kernel(
    const unsigned short* __restrict__ xb, const unsigned short* __restrict__ bt,
    unsigned short* __restrict__ support) {
    __shared__ unsigned short As[128 * 72];
    __shared__ unsigned short Bs[128 * 72];

    const int tid  = threadIdx.x;
    const int lane = tid & 63;
    const int wv   = tid >> 6;
    const int wr   = wv >> 1, wc = wv & 1;
    const long long base = (long long)blockIdx.x * 128;

    v4f acc[4][4] = {};

    for (int k0 = 0; k0 < IN_F; k0 += 64) {
        if (k0) __syncthreads();
        {   // stage A
            const int row = tid >> 1;
            const int kh  = (tid & 1) * 32;
            long long g = base + row;
            unsigned short* dst = &As[row * 72 + kh];
            if (g < N_NODES) {
                const unsigned short* src = xb + g * IN_F + k0 + kh;
                #pragma unroll
                for (int i = 0; i < 4; ++i)
                    *(v8s*)(dst + i * 8) = *(const v8s*)(src + i * 8);
            } else {
                #pragma unroll
                for (int i = 0; i < 4; ++i)
                    *(v8s*)(dst + i * 8) = (v8s){0,0,0,0,0,0,0,0};
            }
        }
        {   // stage B^T
            const int n  = tid >> 1;
            const int kh = (tid & 1) * 32;
            const unsigned short* src = bt + n * IN_F + k0 + kh;
            unsigned short* dst = &Bs[n * 72 + kh];
            #pragma unroll
            for (int i = 0; i < 4; ++i)
                *(v8s*)(dst + i * 8) = *(const v8s*)(src + i * 8);
        }
        __syncthreads();
        #pragma unroll
        for (int ks = 0; ks < 2; ++ks) {
            const int kb = ks * 32 + (lane >> 4) * 8;
            v8s af[4], bf[4];
            #pragma unroll
            for (int t = 0; t < 4; ++t)
                af[t] = *(const v8s*)&As[(wr * 64 + t * 16 + (lane & 15)) * 72 + kb];
            #pragma unroll
            for (int t = 0; t < 4; ++t)
                bf[t] = *(const v8s*)&Bs[(wc * 64 + t * 16 + (lane & 15)) * 72 + kb];
            #pragma unroll
            for (int tm = 0; tm < 4; ++tm)
                #pragma unroll
                for (int tn = 0; tn < 4; ++tn)
                    acc[tm][tn] = __builtin_amdgcn_mfma_f32_16x16x32_bf16(
                        af[tm], bf[tn], acc[tm][tn], 0, 0, 0);
        }
    }
    const int rq = lane >> 4;
    const int cl = lane & 15;
    #pragma unroll
    for (int tm = 0; tm < 4; ++tm) {
        #pragma unroll
        for (int r = 0; r < 4; ++r) {
            long long g = base + wr * 64 + tm * 16 + rq * 4 + r;
            if (g < N_NODES) {
                unsigned short* o = support + g * OUT_F + wc * 64 + cl;
                #pragma unroll
                for (int tn = 0; tn < 4; ++tn)
                    o[tn * 16] = f2bf(acc[tm][tn][r]);
            }
        }
    }
}

__global__ void init_kernel(int* __restrict__ cursor) {
    int i = blockIdx.x * 256 + threadIdx.x;
    if (i < NB) cursor[i * 16] = i * CAP;   // 64B-padded cursors
}

// coalesced bucket scatter: tile -> LDS hist -> scan -> reserve -> reorder -> run writes
__global__ __launch_bounds__(256) void scatter_kernel(
    const int* __restrict__ row, const int* __restrict__ col,
    const float* __restrict__ val, int* __restrict__ cursor,
    int2* __restrict__ cv, int E) {
    __shared__ int cnt[1024];
    __shared__ int loc[1024];
    __shared__ int delta[1024];
    __shared__ int tmp[256];
    __shared__ int gd[TILE];
    __shared__ int2 stage[TILE];
    __shared__ int total_s;
    const int tid = threadIdx.x;
    const int base_e = blockIdx.x * TILE;

    for (int i = tid; i < 1024; i += 256) cnt[i] = 0;
    __syncthreads();
    #pragma unroll
    for (int j = 0; j < TILE / 256; ++j) {
        int e = base_e + j * 256 + tid;
        if (e < E) atomicAdd(&cnt[row[e] >> 7], 1);
    }
    __syncthreads();
    int c0 = cnt[4*tid], c1 = cnt[4*tid+1], c2 = cnt[4*tid+2], c3 = cnt[4*tid+3];
    int s = c0 + c1 + c2 + c3;
    tmp[tid] = s;
    __syncthreads();
    #pragma unroll
    for (int d = 1; d < 256; d <<= 1) {
        int t = (tid >= d) ? tmp[tid - d] : 0;
        __syncthreads();
        tmp[tid] += t;
        __syncthreads();
    }
    int excl = tmp[tid] - s;
    loc[4*tid]   = excl;
    loc[4*tid+1] = excl + c0;
    loc[4*tid+2] = excl + c0 + c1;
    loc[4*tid+3] = excl + c0 + c1 + c2;
    if (tid == 255) total_s = tmp[255];
    __syncthreads();
    for (int i = tid; i < NB; i += 256) {
        int c = cnt[i];
        int gbase = 0;
        if (c > 0) gbase = atomicAdd(&cursor[i * 16], c);
        delta[i] = gbase - loc[i];
        cnt[i] = loc[i];
    }
    __syncthreads();
    #pragma unroll
    for (int j = 0; j < TILE / 256; ++j) {
        int e = base_e + j * 256 + tid;
        if (e < E) {
            int r = row[e];
            int b = r >> 7;
            int rank = atomicAdd(&cnt[b], 1);
            stage[rank] = make_int2(col[e] | ((r & 127) << 17), __float_as_int(val[e]));
            gd[rank] = delta[b] + rank;
        }
    }
    __syncthreads();
    int total = total_s;
    for (int i = tid; i < total; i += 256)
        cv[gd[i]] = stage[i];
}

// per-bucket: LDS counting-sort by local row, then csr-style register-accumulate gather
__global__ __launch_bounds__(256) void acc2_kernel(
    const int* __restrict__ cursor, const int2* __restrict__ cv,
    const unsigned short* __restrict__ support, float* __restrict__ out) {
    __shared__ int2 sorted[CAP];     // 20.5 KB
    __shared__ int cnt_s[128];
    __shared__ int start_s[128];
    __shared__ int pos_s[128];
    const int tid = threadIdx.x;
    const int b = blockIdx.x;
    const int e0 = b * CAP;
    const int nE = cursor[b * 16] - e0;

    if (tid < 128) cnt_s[tid] = 0;
    __syncthreads();
    // pass 1: histogram by local row
    for (int i = tid; i < nE; i += 256)
        atomicAdd(&cnt_s[cv[e0 + i].x >> 17], 1);
    __syncthreads();
    // scan 128 bins (Hillis-Steele on first 128 threads; barriers block-wide)
    int v = (tid < 128) ? cnt_s[tid] : 0;
    int sc = v;
    if (tid < 128) pos_s[tid] = sc;
    __syncthreads();
    #pragma unroll
    for (int d = 1; d < 128; d <<= 1) {
        int t = (tid >= d && tid < 128) ? pos_s[tid - d] : 0;
        __syncthreads();
        if (tid < 128) pos_s[tid] += t;
        __syncthreads();
    }
    if (tid < 128) {
        int st = pos_s[tid] - v;   // exclusive
        start_s[tid] = st;
        pos_s[tid] = st;           // cursor for reorder
    }
    __syncthreads();
    // pass 2: reorder into row-sorted LDS
    for (int i = tid; i < nE; i += 256) {
        int2 c = cv[e0 + i];
        int rank = atomicAdd(&pos_s[c.x >> 17], 1);
        sorted[rank] = c;
    }
    __syncthreads();
    // gather: wave w owns rows w*32 .. w*32+31, register accumulate, one write/row
    const int lane = tid & 63, w = tid >> 6;
    const long long rowbase = (long long)b * 128;
    for (int rr = 0; rr < 32; ++rr) {
        int rl = w * 32 + rr;
        int e = start_s[rl];
        int end = e + cnt_s[rl];
        float a0 = 0.f, a1 = 0.f;
        for (; e < end; e += 4) {
            #pragma unroll
            for (int j = 0; j < 4; ++j) {
                int idx = e + j;
                int ids = min(idx, end - 1);
                int2 c = sorted[ids];
                float vv = (idx < end) ? __int_as_float(c.y) : 0.0f;
                int colv = c.x & 131071;
                unsigned int u = *(const unsigned int*)(support + colv * OUT_F + lane * 2);
                a0 = fmaf(vv, bf2f((unsigned short)(u & 0xffff)), a0);
                a1 = fmaf(vv, bf2f((unsigned short)(u >> 16)), a1);
            }
        }
        long long g = rowbase + rl;
        if (g < N_NODES)
            *(float2*)(out + g * OUT_F + lane * 2) = make_float2(a0, a1);
    }
}

extern "C" void kernel_launch(void* const* d_in, const int* in_sizes, int n_in,
                              void* d_out, int out_size, void* d_ws, size_t ws_size,
                              hipStream_t stream) {
    const float* input   = (const float*)d_in[0];
    const float* weight  = (const float*)d_in[1];
    const int*   adj_row = (const int*)d_in[2];
    const int*   adj_col = (const int*)d_in[3];
    const float* adj_val = (const float*)d_in[4];
    const float* drop_u  = (const float*)d_in[5];
    float* out = (float*)d_out;
    const int E = in_sizes[2];

    // ws layout: bt 64K | xb bf16 51.2M (cv int2 16M aliases xb - disjoint lifetimes:
    // xb dead after gemm, cv born at scatter) | support bf16 25.6M | cursor 50K
    char* p = (char*)d_ws;
    unsigned short* bt      = (unsigned short*)p;  p += 65536;
    unsigned short* xb      = (unsigned short*)p;
    int2*           cv      = (int2*)p;            p += (size_t)N_NODES * IN_F * 2;
    unsigned short* support = (unsigned short*)p;  p += (size_t)N_NODES * OUT_F * 2;
    int*            cursor  = (int*)p;

    init_kernel<<<4, 256, 0, stream>>>(cursor);
    drop_kernel<<<2048, 256, 0, stream>>>(input, drop_u, xb, N_NODES * IN_F / 4);
    wt_kernel<<<128, 256, 0, stream>>>(weight, bt);
    gemm_kernel<<<(N_NODES + 127) / 128, 256, 0, stream>>>(xb, bt, support);
    scatter_kernel<<<(E + TILE - 1) / TILE, 256, 0, stream>>>(adj_row, adj_col, adj_val, cursor, cv, E);
    acc2_kernel<<<NB, 256, 0, stream>>>(cursor, cv, support, out);
}